// Round 12
// baseline (9755.746 us; speedup 1.0000x reference)
//
#include <hip/hip_runtime.h>
#include <cstdint>

#define NPTS 32768
#define DIM  256
#define NK   128
#define NITER 100
#define NBLK 256
#define NTHR 1024

typedef unsigned short ushort_t;
typedef unsigned long long ull_t;
typedef __attribute__((ext_vector_type(8))) short s8v;   // 8 bf16 in 4 VGPRs
typedef __attribute__((ext_vector_type(4))) float f4v;   // MFMA accumulator

__device__ __forceinline__ unsigned short f2bf(float f) {
  unsigned u = __float_as_uint(f);
  u += 0x7fffu + ((u >> 16) & 1u);      // RTNE
  return (unsigned short)(u >> 16);
}
__device__ __forceinline__ float bf2f(unsigned short b) {
  return __uint_as_float(((unsigned)b) << 16);
}

// agent-scope (LLC-coherent) accesses — bypass non-coherent L1/L2; no
// __threadfence needed for data moved through them (proven R8-R11).
__device__ __forceinline__ void cstore(float* p, float v) {
  __hip_atomic_store(p, v, __ATOMIC_RELAXED, __HIP_MEMORY_SCOPE_AGENT);
}
__device__ __forceinline__ float cload(const float* p) {
  return __hip_atomic_load(p, __ATOMIC_RELAXED, __HIP_MEMORY_SCOPE_AGENT);
}
__device__ __forceinline__ void cstorei(int* p, int v) {
  __hip_atomic_store(p, v, __ATOMIC_RELAXED, __HIP_MEMORY_SCOPE_AGENT);
}
__device__ __forceinline__ int cloadi(const int* p) {
  return __hip_atomic_load(p, __ATOMIC_RELAXED, __HIP_MEMORY_SCOPE_AGENT);
}
__device__ __forceinline__ void cstore64(ull_t* p, ull_t v) {
  __hip_atomic_store(p, v, __ATOMIC_RELAXED, __HIP_MEMORY_SCOPE_AGENT);
}
__device__ __forceinline__ ull_t cload64(const ull_t* p) {
  return __hip_atomic_load(p, __ATOMIC_RELAXED, __HIP_MEMORY_SCOPE_AGENT);
}
__device__ __forceinline__ f4v cload128f(const ull_t* p) {
  ull_t a = cload64(p), b = cload64(p + 1);
  f4v r;
  r[0] = __uint_as_float((unsigned)a); r[1] = __uint_as_float((unsigned)(a >> 32));
  r[2] = __uint_as_float((unsigned)b); r[3] = __uint_as_float((unsigned)(b >> 32));
  return r;
}

// Stage one 32KB half-D x tile via global_load_lds (linear LDS dest,
// pre-swizzled global source). LDS[G] = global[G ^ (row&7)], 16B granules.
__device__ __forceinline__ void stage4(const ushort_t* __restrict__ src, s8v* buf, int h, int t) {
  const int lane = t & 63;
  const int wb = (t >> 6) << 6;           // wave-uniform base granule
#pragma unroll
  for (int i = 0; i < 2; ++i) {
    const int Gb = i * 1024 + wb;
    const int G  = Gb + lane;
    const int Gs = G ^ ((G >> 4) & 7);
    const char* ga = (const char*)src + (G >> 4) * 512 + h * 256 + (Gs & 15) * 16;
    __builtin_amdgcn_global_load_lds(
        (const __attribute__((address_space(1))) void*)ga,
        (__attribute__((address_space(3))) void*)((char*)buf + Gb * 16),
        16, 0, 0);
  }
}

// Stage centroid hi/lo half-D tiles from the packed coherent image.
__device__ __forceinline__ void stage_c(const ull_t* __restrict__ cpk,
                                        s8v* bh, s8v* bl, int h, int t) {
#pragma unroll
  for (int i = 0; i < 2; ++i) {
    const int G = i * NTHR + t;           // granule id [0,2048)
    const int k = G >> 4, gcol = G & 15;
    const int sc2 = gcol ^ (k & 7);       // swizzled source column
    const ull_t* src = cpk + (size_t)k * 128 + h * 64 + sc2 * 4;
    ull_t w0 = cload64(src + 0), w1 = cload64(src + 1);
    ull_t w2 = cload64(src + 2), w3 = cload64(src + 3);
    s8v vh, vl;
    vh[0] = (short)w0; vl[0] = (short)(w0 >> 16); vh[1] = (short)(w0 >> 32); vl[1] = (short)(w0 >> 48);
    vh[2] = (short)w1; vl[2] = (short)(w1 >> 16); vh[3] = (short)(w1 >> 32); vl[3] = (short)(w1 >> 48);
    vh[4] = (short)w2; vl[4] = (short)(w2 >> 16); vh[5] = (short)(w2 >> 32); vl[5] = (short)(w2 >> 48);
    vh[6] = (short)w3; vl[6] = (short)(w3 >> 16); vh[7] = (short)(w3 >> 32); vl[7] = (short)(w3 >> 48);
    *(s8v*)((char*)bh + G * 16) = vh;
    *(s8v*)((char*)bl + G * 16) = vl;
  }
}

// ---- low-pressure all-to-all grid barrier: 64 lanes poll 4 flags each ----
__device__ __forceinline__ void poll_flags(unsigned* flags, unsigned gen, int t) {
  if (t < 64) {
#pragma unroll
    for (int q = 0; q < 4; ++q) {
      while (__hip_atomic_load(&flags[(q * 64 + t) * 16], __ATOMIC_RELAXED, __HIP_MEMORY_SCOPE_AGENT) < gen)
        __builtin_amdgcn_s_sleep(8);
    }
  }
}
__device__ __forceinline__ void gbar(unsigned* flags, unsigned gen) {
  __syncthreads();
  if (threadIdx.x == 0)
    __hip_atomic_store(&flags[blockIdx.x * 16], gen, __ATOMIC_RELAXED, __HIP_MEMORY_SCOPE_AGENT);
  poll_flags(flags, gen, threadIdx.x);
  asm volatile("" ::: "memory");
  __syncthreads();
}
// barrier that issues next GEMM's x half-0 DMA prefetch inside the window
__device__ __forceinline__ void gbar_pf(unsigned* flags, unsigned gen,
    const ushort_t* xhb, const ushort_t* xlb, s8v (*bufs)[2048], int t) {
  __syncthreads();
  stage4(xhb, bufs[0], 0, t);             // own immutable tile: race-free
  stage4(xlb, bufs[1], 0, t);
  if (t == 0)
    __hip_atomic_store(&flags[blockIdx.x * 16], gen, __ATOMIC_RELAXED, __HIP_MEMORY_SCOPE_AGENT);
  poll_flags(flags, gen, t);
  asm volatile("" ::: "memory");
  __syncthreads();
}

struct SMa {
  union {
    s8v bufs[4][2048];        // XH, XL, CH, CL half-D tiles = 128 KB (phase A)
    float accB[NK * DIM];     // swizzled segment-sum accumulator (phase B)
  } u;
  float cns[NK];
  float redd[NK * 4];
  int   redk[NK * 4];
  float gmaxs[NK];
  float labvs[NK];
  int   labis[NK];
};
union ScU {                   // phase-exclusive small scratch (4 KB)
  float red4[1024];
  float redcn[1024];
};

// 16-wave (4x4) 3-pass hi/lo bf16 MFMA GEMM: acc[i][j][r] = x_p . c_k.
__device__ __forceinline__ void gemm_core(
    SMa& sm, int t,
    const ushort_t* __restrict__ xhb, const ushort_t* __restrict__ xlb,
    const ull_t* __restrict__ cpk, const float* __restrict__ cn2, f4v (&acc)[2][2]) {
  const int lane = t & 63;
  const int w    = t >> 6;
  const int wr   = w >> 2, wc = w & 3;    // 4x4 wave grid
  const int g    = lane >> 4, lr = lane & 15;

  if (t < NK) sm.cns[t] = cload(&cn2[2 * t]) + cload(&cn2[2 * t + 1]);

  const f4v zero = {0.f, 0.f, 0.f, 0.f};
#pragma unroll
  for (int i = 0; i < 2; ++i)
#pragma unroll
    for (int j = 0; j < 2; ++j) acc[i][j] = zero;

  const int swz = (lr & 7) << 4;
  int a_off[2], b_off[2];
#pragma unroll
  for (int i = 0; i < 2; ++i) a_off[i] = (wr * 32 + i * 16 + lr) * 256 + g * 16;
#pragma unroll
  for (int j = 0; j < 2; ++j) b_off[j] = (wc * 32 + j * 16 + lr) * 256 + g * 16;

  for (int h = 0; h < 2; ++h) {           // two D-halves of 128
    if (h == 1) {                         // issue DMA first for overlap
      stage4(xhb, sm.u.bufs[0], 1, t);
      stage4(xlb, sm.u.bufs[1], 1, t);
    }
    stage_c(cpk, sm.u.bufs[2], sm.u.bufs[3], h, t);
    __syncthreads();                      // DMA + cloads + ds_writes landed
#pragma unroll
    for (int kk = 0; kk < 4; ++kk) {      // K=128 per half, 4 steps of 32
      s8v ah[2], al[2], bh[2], bl[2];
#pragma unroll
      for (int i = 0; i < 2; ++i) {
        int o = (a_off[i] + kk * 64) ^ swz;
        ah[i] = *(const s8v*)((const char*)sm.u.bufs[0] + o);
        al[i] = *(const s8v*)((const char*)sm.u.bufs[1] + o);
      }
#pragma unroll
      for (int j = 0; j < 2; ++j) {
        int o = (b_off[j] + kk * 64) ^ swz;
        bh[j] = *(const s8v*)((const char*)sm.u.bufs[2] + o);
        bl[j] = *(const s8v*)((const char*)sm.u.bufs[3] + o);
      }
#pragma unroll
      for (int i = 0; i < 2; ++i)
#pragma unroll
        for (int j = 0; j < 2; ++j) {
          acc[i][j] = __builtin_amdgcn_mfma_f32_16x16x32_bf16(ah[i], bh[j], acc[i][j], 0, 0, 0);
          acc[i][j] = __builtin_amdgcn_mfma_f32_16x16x32_bf16(ah[i], bl[j], acc[i][j], 0, 0, 0);
          acc[i][j] = __builtin_amdgcn_mfma_f32_16x16x32_bf16(al[i], bh[j], acc[i][j], 0, 0, 0);
        }
    }
    if (h == 0) __syncthreads();          // half-0 reads done before overwrite
  }
}

__global__ __launch_bounds__(NTHR, 1) void kmeans_fused(
    const float* __restrict__ x, const int* __restrict__ init_idx,
    ushort_t* __restrict__ xh, ushort_t* __restrict__ xl,
    ull_t* __restrict__ cpk, float* __restrict__ cn2, int* __restrict__ ids,
    float* __restrict__ psum, float* __restrict__ pcnt,
    float* __restrict__ outp, unsigned* __restrict__ flags,
    float* __restrict__ out) {
  __shared__ SMa sm;
  __shared__ ScU sc;
  __shared__ int ids_loc[NK];
  __shared__ int cntB[NK];
  __shared__ float cnt4[4];
  __shared__ ushort_t hsm[DIM], lsm[DIM];

  const int b = blockIdx.x;
  const int t = threadIdx.x;
  const int lane = t & 63;
  const int w  = t >> 6;
  const int wr = w >> 2, wc = w & 3;
  const int g  = lane >> 4, lr = lane & 15;
  const int pbase = b * 128;
  const ushort_t* xhb = xh + (size_t)pbase * DIM;
  const ushort_t* xlb = xl + (size_t)pbase * DIM;
  unsigned gen = 1;

  // ---------------- prep: x -> bf16 hi/lo images (own tile only) ----------------
  for (int i = 0; i < 4; ++i) {
    int gg = b * 4096 + i * NTHR + t;
    const float4* src = (const float4*)x + gg * 2;
    float4 fa = src[0], fb = src[1];
    float vv[8] = {fa.x, fa.y, fa.z, fa.w, fb.x, fb.y, fb.z, fb.w};
    s8v vh, vl;
#pragma unroll
    for (int j = 0; j < 8; ++j) {
      unsigned short hh = f2bf(vv[j]);
      vh[j] = (short)hh;
      vl[j] = (short)f2bf(vv[j] - bf2f(hh));
    }
    ((s8v*)xh)[gg] = vh;
    ((s8v*)xl)[gg] = vl;
  }

  // ---------------- init: c0 = x[init_idx] -> packed image + cn2 ----------------
  if (b < NK) {
    float eff = 0.f;
    if (t < DIM) {
      float v = x[init_idx[b] * DIM + t];
      unsigned short hh = f2bf(v);
      unsigned short ll = f2bf(v - bf2f(hh));
      hsm[t] = hh; lsm[t] = ll;
      eff = bf2f(hh) + bf2f(ll);
    }
    __syncthreads();
    sc.redcn[t] = (t < DIM) ? eff * eff : 0.f;
    if (t < NK) {
      ull_t wv = (ull_t)hsm[2 * t] | ((ull_t)lsm[2 * t] << 16)
               | ((ull_t)hsm[2 * t + 1] << 32) | ((ull_t)lsm[2 * t + 1] << 48);
      cstore64(&cpk[(size_t)b * 128 + t], wv);
    }
    __syncthreads();
    for (int s = 512; s > 0; s >>= 1) { if (t < s) sc.redcn[t] += sc.redcn[t + s]; __syncthreads(); }
    if (t == 0) { cstore(&cn2[b * 2], sc.redcn[0]); cstore(&cn2[b * 2 + 1], 0.f); }
  }
  gbar_pf(flags, gen, xhb, xlb, sm.u.bufs, t); ++gen;

  // ---------------- main loop: 2 barriers per iteration ----------------
  for (int it = 0; it < NITER; ++it) {
    // ---- phase A: assign (ids stay block-local) ----
    {
      f4v acc[2][2];
      gemm_core(sm, t, xhb, xlb, cpk, cn2, acc);
#pragma unroll
      for (int i = 0; i < 2; ++i) {
#pragma unroll
        for (int r = 0; r < 4; ++r) {
          int prow = wr * 32 + i * 16 + g * 4 + r;
          float bd = 1e30f; int bk = 0;
#pragma unroll
          for (int j = 0; j < 2; ++j) {
            int col = wc * 32 + j * 16 + lr;
            float s = sm.cns[col] - 2.f * acc[i][j][r];
            if (s < bd || (s == bd && col < bk)) { bd = s; bk = col; }
          }
#pragma unroll
          for (int msk = 1; msk < 16; msk <<= 1) {
            float od = __shfl_xor(bd, msk, 64);
            int   ok = __shfl_xor(bk, msk, 64);
            if (od < bd || (od == bd && ok < bk)) { bd = od; bk = ok; }
          }
          if (lr == 0) { sm.redd[prow * 4 + wc] = bd; sm.redk[prow * 4 + wc] = bk; }
        }
      }
      __syncthreads();                    // also: all bufs reads complete
      if (t < NK) {
        float bd = sm.redd[t * 4]; int bk = sm.redk[t * 4];
#pragma unroll
        for (int q = 1; q < 4; ++q) {
          float dq = sm.redd[t * 4 + q]; int kq = sm.redk[t * 4 + q];
          if (dq < bd || (dq == bd && kq < bk)) { bd = dq; bk = kq; }
        }
        ids_loc[t] = bk;
        if (it == NITER - 1) cstorei(&ids[pbase + t], bk);  // loss labels
      }
      // ---- phase B (fused, no barrier): own-point segment sums ----
#pragma unroll
      for (int i = 0; i < 32; ++i) sm.u.accB[i * NTHR + t] = 0.f;
      if (t < NK) cntB[t] = 0;
      __syncthreads();                    // accB zeroed + ids_loc visible
      {
        const int p = t >> 3, dc = t & 7;
        const int id = ids_loc[p];
        if (dc == 0) atomicAdd(&cntB[id], 1);
        const ull_t* xr = (const ull_t*)(x + ((size_t)pbase + p) * DIM + dc * 32);
        f4v v0 = cload128f(xr + 0),  v1 = cload128f(xr + 2);
        f4v v2 = cload128f(xr + 4),  v3 = cload128f(xr + 6);
        f4v v4 = cload128f(xr + 8),  v5 = cload128f(xr + 10);
        f4v v6 = cload128f(xr + 12), v7 = cload128f(xr + 14);
        // swizzled row: elem d=dc*32+j stored at [id*256 + dc*32 + (j ^ sw)]
        const int sw = (id & 31) ^ ((dc * 4) & 31);
        float* ab = &sm.u.accB[id * 256 + dc * 32];
        atomicAdd(&ab[0 ^ sw],  v0[0]); atomicAdd(&ab[1 ^ sw],  v0[1]);
        atomicAdd(&ab[2 ^ sw],  v0[2]); atomicAdd(&ab[3 ^ sw],  v0[3]);
        atomicAdd(&ab[4 ^ sw],  v1[0]); atomicAdd(&ab[5 ^ sw],  v1[1]);
        atomicAdd(&ab[6 ^ sw],  v1[2]); atomicAdd(&ab[7 ^ sw],  v1[3]);
        atomicAdd(&ab[8 ^ sw],  v2[0]); atomicAdd(&ab[9 ^ sw],  v2[1]);
        atomicAdd(&ab[10 ^ sw], v2[2]); atomicAdd(&ab[11 ^ sw], v2[3]);
        atomicAdd(&ab[12 ^ sw], v3[0]); atomicAdd(&ab[13 ^ sw], v3[1]);
        atomicAdd(&ab[14 ^ sw], v3[2]); atomicAdd(&ab[15 ^ sw], v3[3]);
        atomicAdd(&ab[16 ^ sw], v4[0]); atomicAdd(&ab[17 ^ sw], v4[1]);
        atomicAdd(&ab[18 ^ sw], v4[2]); atomicAdd(&ab[19 ^ sw], v4[3]);
        atomicAdd(&ab[20 ^ sw], v5[0]); atomicAdd(&ab[21 ^ sw], v5[1]);
        atomicAdd(&ab[22 ^ sw], v5[2]); atomicAdd(&ab[23 ^ sw], v5[3]);
        atomicAdd(&ab[24 ^ sw], v6[0]); atomicAdd(&ab[25 ^ sw], v6[1]);
        atomicAdd(&ab[26 ^ sw], v6[2]); atomicAdd(&ab[27 ^ sw], v6[3]);
        atomicAdd(&ab[28 ^ sw], v7[0]); atomicAdd(&ab[29 ^ sw], v7[1]);
        atomicAdd(&ab[30 ^ sw], v7[2]); atomicAdd(&ab[31 ^ sw], v7[3]);
      }
      __syncthreads();
      // flush partials linear: psum[b][k][d]
#pragma unroll
      for (int i = 0; i < 32; ++i) {
        int idx = i * NTHR + t;
        int k2 = idx >> 8, d2 = idx & 255;
        int dc2 = d2 >> 5, j2 = d2 & 31;
        float v = sm.u.accB[k2 * 256 + dc2 * 32 + (j2 ^ (k2 & 31) ^ ((dc2 * 4) & 31))];
        cstore(&psum[(size_t)b * (NK * DIM) + idx], v);
      }
      if (t < NK) cstore(&pcnt[(size_t)b * NK + t], (float)cntB[t]);
    }
    gbar_pf(flags, gen, xhb, xlb, sm.u.bufs, t); ++gen;   // + prefetch next x half-0

    // ---- phase C: 256 blocks = 128 clusters x 2 D-halves ----
    {
      const int k = b >> 1, hh2 = b & 1;
      const int pbq = t >> 7, dwh = t & 127;
      const int d = hh2 * 128 + dwh;
      float s = 0.f;
#pragma unroll 8
      for (int pb = pbq * 32; pb < pbq * 32 + 32; ++pb)
        s += cload(&psum[(size_t)pb * (NK * DIM) + k * 256 + d]);
      sc.red4[pbq * 128 + dwh] = s;
      float cv = (t < NBLK) ? cload(&pcnt[(size_t)t * NK + k]) : 0.f;
      if (t < NBLK) {
#pragma unroll
        for (int m = 1; m < 64; m <<= 1) cv += __shfl_xor(cv, m, 64);
        if (lane == 0) cnt4[w] = cv;
      }
      __syncthreads();
      float eff = 0.f;
      if (t < 128) {
        float cnt = cnt4[0] + cnt4[1] + cnt4[2] + cnt4[3];
        float ssum = 0.f;
#pragma unroll
        for (int ww = 0; ww < 8; ++ww) ssum += sc.red4[ww * 128 + t];
        float mean = ssum / cnt;          // NaN if empty, as ref
        unsigned short hh = f2bf(mean);
        unsigned short ll = f2bf(mean - bf2f(hh));
        hsm[t] = hh; lsm[t] = ll;
        eff = bf2f(hh) + bf2f(ll);
      }
      __syncthreads();                    // red4 reads + hsm/lsm writes done
      sc.redcn[t] = (t < 128) ? eff * eff : 0.f;
      if (t < 64) {
        ull_t wv = (ull_t)hsm[2 * t] | ((ull_t)lsm[2 * t] << 16)
                 | ((ull_t)hsm[2 * t + 1] << 32) | ((ull_t)lsm[2 * t + 1] << 48);
        cstore64(&cpk[(size_t)k * 128 + hh2 * 64 + t], wv);
      }
      __syncthreads();
      for (int st = 512; st > 0; st >>= 1) { if (t < st) sc.redcn[t] += sc.redcn[t + st]; __syncthreads(); }
      if (t == 0) cstore(&cn2[k * 2 + hh2], sc.redcn[0]);
    }
    gbar(flags, gen); ++gen;
  }

  // ---------------- final: loss (log-softmax + CE), deterministic reduce ----------------
  {
    f4v acc[2][2];
    gemm_core(sm, t, xhb, xlb, cpk, cn2, acc);
#pragma unroll
    for (int i = 0; i < 2; ++i) {
#pragma unroll
      for (int r = 0; r < 4; ++r) {
        int prow = wr * 32 + i * 16 + g * 4 + r;
        float m = -1e30f;
#pragma unroll
        for (int j = 0; j < 2; ++j) m = fmaxf(m, acc[i][j][r]);
#pragma unroll
        for (int msk = 1; msk < 16; msk <<= 1) m = fmaxf(m, __shfl_xor(m, msk, 64));
        if (lr == 0) sm.redd[prow * 4 + wc] = m;
      }
    }
    __syncthreads();
    if (t < NK) {
      float m = sm.redd[t * 4];
#pragma unroll
      for (int q = 1; q < 4; ++q) m = fmaxf(m, sm.redd[t * 4 + q]);
      sm.gmaxs[t] = m;
      sm.labis[t] = cloadi(&ids[pbase + t]);
    }
    __syncthreads();
#pragma unroll
    for (int i = 0; i < 2; ++i) {
#pragma unroll
      for (int r = 0; r < 4; ++r) {
        int prow = wr * 32 + i * 16 + g * 4 + r;
        float m = sm.gmaxs[prow];
        int lab = sm.labis[prow];
        float s = 0.f;
#pragma unroll
        for (int j = 0; j < 2; ++j) {
          int col = wc * 32 + j * 16 + lr;
          float v = acc[i][j][r];
          s += expf(v - m);
          if (col == lab) sm.labvs[prow] = v;
        }
#pragma unroll
        for (int msk = 1; msk < 16; msk <<= 1) s += __shfl_xor(s, msk, 64);
        if (lr == 0) sm.redd[prow * 4 + wc] = s;
      }
    }
    __syncthreads();
    if (t < NK) {
      float se = sm.redd[t * 4] + sm.redd[t * 4 + 1] + sm.redd[t * 4 + 2] + sm.redd[t * 4 + 3];
      float lse = sm.gmaxs[t] + logf(se);
      sm.gmaxs[t] = lse - sm.labvs[t];
    }
    __syncthreads();
    if (t == 0) {
      float tot = 0.f;
      for (int q = 0; q < NK; ++q) tot += sm.gmaxs[q];
      cstore(&outp[b], tot);
    }
  }
  gbar(flags, gen); ++gen;
  if (b == 0) {
    sc.redcn[t] = (t < NBLK) ? cload(&outp[t]) : 0.f;
    __syncthreads();
    for (int s = 512; s > 0; s >>= 1) { if (t < s) sc.redcn[t] += sc.redcn[t + s]; __syncthreads(); }
    if (t == 0) out[0] = sc.redcn[0] * (1.0f / (float)NPTS);
  }
}

extern "C" void kernel_launch(void* const* d_in, const int* in_sizes, int n_in,
                              void* d_out, int out_size, void* d_ws, size_t ws_size,
                              hipStream_t stream) {
  const float* x        = (const float*)d_in[0];
  const int*   init_idx = (const int*)d_in[1];
  float* out = (float*)d_out;
  char* ws = (char*)d_ws;

  // ws layout (bytes):
  ushort_t* xh  = (ushort_t*)(ws);                    // 16777216
  ushort_t* xl  = (ushort_t*)(ws + 16777216);         // 16777216
  ull_t* cpk  = (ull_t*)(ws + 33554432);              // 131072
  float* cn2  = (float*)(ws + 33685504);              // 1024
  int*   ids  = (int*)(ws + 33686528);                // 131072
  float* psum = (float*)(ws + 33817600);              // 256*128*256*4 = 33554432
  float* pcnt = (float*)(ws + 67372032);              // 256*128*4 = 131072
  float* outp = (float*)(ws + 67503104);              // 1024
  unsigned* flags = (unsigned*)(ws + 67504128);       // 256*64B = 16384

  // reset barrier state every launch (graph replays include this node)
  hipMemsetAsync(flags, 0, 16384, stream);
  kmeans_fused<<<dim3(NBLK), dim3(NTHR), 0, stream>>>(
      x, init_idx, xh, xl, cpk, cn2, ids, psum, pcnt, outp, flags, out);
}

// Round 13
// 7533.936 us; speedup vs baseline: 1.2949x; 1.2949x over previous
//
#include <hip/hip_runtime.h>
#include <cstdint>

#define NPTS 32768
#define DIM  256
#define NK   128
#define NITER 100
#define NBLK 256
#define NTHR 1024
#define PAD  33

typedef unsigned short ushort_t;
typedef unsigned long long ull_t;
typedef __attribute__((ext_vector_type(8))) short s8v;   // 8 bf16 in 4 VGPRs
typedef __attribute__((ext_vector_type(4))) float f4v;   // MFMA accumulator

__device__ __forceinline__ unsigned short f2bf(float f) {
  unsigned u = __float_as_uint(f);
  u += 0x7fffu + ((u >> 16) & 1u);      // RTNE
  return (unsigned short)(u >> 16);
}
__device__ __forceinline__ float bf2f(unsigned short b) {
  return __uint_as_float(((unsigned)b) << 16);
}

// agent-scope (LLC-coherent) accesses — bypass non-coherent L1/L2
__device__ __forceinline__ void cstore(float* p, float v) {
  __hip_atomic_store(p, v, __ATOMIC_RELAXED, __HIP_MEMORY_SCOPE_AGENT);
}
__device__ __forceinline__ float cload(const float* p) {
  return __hip_atomic_load(p, __ATOMIC_RELAXED, __HIP_MEMORY_SCOPE_AGENT);
}
__device__ __forceinline__ void cstorei(int* p, int v) {
  __hip_atomic_store(p, v, __ATOMIC_RELAXED, __HIP_MEMORY_SCOPE_AGENT);
}
__device__ __forceinline__ int cloadi(const int* p) {
  return __hip_atomic_load(p, __ATOMIC_RELAXED, __HIP_MEMORY_SCOPE_AGENT);
}
__device__ __forceinline__ void cstore64(ull_t* p, ull_t v) {
  __hip_atomic_store(p, v, __ATOMIC_RELAXED, __HIP_MEMORY_SCOPE_AGENT);
}
__device__ __forceinline__ f4v cload128f(const ull_t* p) {
  ull_t a = __hip_atomic_load(p, __ATOMIC_RELAXED, __HIP_MEMORY_SCOPE_AGENT);
  ull_t b = __hip_atomic_load(p + 1, __ATOMIC_RELAXED, __HIP_MEMORY_SCOPE_AGENT);
  f4v r;
  r[0] = __uint_as_float((unsigned)a); r[1] = __uint_as_float((unsigned)(a >> 32));
  r[2] = __uint_as_float((unsigned)b); r[3] = __uint_as_float((unsigned)(b >> 32));
  return r;
}

// ---- all-to-all 1-hop grid barrier; 64 lanes poll 4 flags each.
// inv=true: acquire __threadfence after all arrivals (L2/L1 invalidate) so
// subsequent NORMAL loads (cpk staging) see agent-scope writes.
__device__ __forceinline__ void gbar(unsigned* flags, unsigned gen, bool inv) {
  __syncthreads();                        // drain all vmem (cstores visible)
  if (threadIdx.x == 0)
    __hip_atomic_store(&flags[blockIdx.x * 16], gen, __ATOMIC_RELAXED, __HIP_MEMORY_SCOPE_AGENT);
  if (threadIdx.x < 64) {
#pragma unroll
    for (int q = 0; q < 4; ++q) {
      while (__hip_atomic_load(&flags[(q * 64 + threadIdx.x) * 16], __ATOMIC_RELAXED, __HIP_MEMORY_SCOPE_AGENT) < gen)
        __builtin_amdgcn_s_sleep(8);
    }
  }
  __syncthreads();                        // all 256 arrivals observed
  if (inv && threadIdx.x == 0) __threadfence();
  asm volatile("" ::: "memory");
  __syncthreads();
}

union StU {                 // phase-exclusive LDS scratch (20.5 KB)
  struct { char ch[128 * 80]; char cl[128 * 80]; } a;       // GEMM C-eighth tiles (padded rows)
  struct { float accB[NK * PAD]; ushort_t idsl16[1024]; } b;
  struct { float red4[1024]; float redcn[1024]; } c;
};

// 16-wave (4x4) 3-pass hi/lo bf16 MFMA GEMM over 8 D-eighths (32 dims each).
// A-operand: resident swizzled LDS x-image. B-operand: cpk staged per eighth
// via NORMAL loads (L2-shared per XCD; freshness via C->A acquire fence).
__device__ __forceinline__ void gemm_core(
    const s8v* __restrict__ xhR, const s8v* __restrict__ xlR,
    StU& u, float* cns, int t,
    const ull_t* __restrict__ cpk, const float* __restrict__ cn2, f4v (&acc)[2][2]) {
  const int lane = t & 63;
  const int w    = t >> 6;
  const int wr   = w >> 2, wc = w & 3;    // 4x4 wave grid
  const int g    = lane >> 4, lr = lane & 15;

  if (t < NK) cns[t] = cload(&cn2[2 * t]) + cload(&cn2[2 * t + 1]);

  const f4v zero = {0.f, 0.f, 0.f, 0.f};
#pragma unroll
  for (int i = 0; i < 2; ++i)
#pragma unroll
    for (int j = 0; j < 2; ++j) acc[i][j] = zero;

  for (int q = 0; q < 8; ++q) {           // eighths: dims q*32..q*32+31
    if (t < 512) {                        // stage CH/CL eighth (normal loads)
      int row = t >> 2, c = t & 3;        // row=cluster, c=granule (8 dims)
      const ull_t* src = cpk + (size_t)row * 128 + q * 16 + c * 4;
      ull_t w0 = src[0], w1 = src[1], w2 = src[2], w3 = src[3];
      s8v vh, vl;
      vh[0] = (short)w0; vl[0] = (short)(w0 >> 16); vh[1] = (short)(w0 >> 32); vl[1] = (short)(w0 >> 48);
      vh[2] = (short)w1; vl[2] = (short)(w1 >> 16); vh[3] = (short)(w1 >> 32); vl[3] = (short)(w1 >> 48);
      vh[4] = (short)w2; vl[4] = (short)(w2 >> 16); vh[5] = (short)(w2 >> 32); vl[5] = (short)(w2 >> 48);
      vh[6] = (short)w3; vl[6] = (short)(w3 >> 16); vh[7] = (short)(w3 >> 32); vl[7] = (short)(w3 >> 48);
      *(s8v*)(u.a.ch + row * 80 + c * 16) = vh;
      *(s8v*)(u.a.cl + row * 80 + c * 16) = vl;
    }
    __syncthreads();                      // stage landed; prev eighth reads done
    s8v ah[2], al[2], bh[2], bl[2];
#pragma unroll
    for (int i = 0; i < 2; ++i) {
      int ra = wr * 32 + i * 16 + lr;
      int o = ra * 512 + (((q * 4 + g) ^ (lr & 7)) * 16);
      ah[i] = *(const s8v*)((const char*)xhR + o);
      al[i] = *(const s8v*)((const char*)xlR + o);
    }
#pragma unroll
    for (int j = 0; j < 2; ++j) {
      int rb = wc * 32 + j * 16 + lr;
      int o = rb * 80 + g * 16;
      bh[j] = *(const s8v*)(u.a.ch + o);
      bl[j] = *(const s8v*)(u.a.cl + o);
    }
#pragma unroll
    for (int i = 0; i < 2; ++i)
#pragma unroll
      for (int j = 0; j < 2; ++j) {
        acc[i][j] = __builtin_amdgcn_mfma_f32_16x16x32_bf16(ah[i], bh[j], acc[i][j], 0, 0, 0);
        acc[i][j] = __builtin_amdgcn_mfma_f32_16x16x32_bf16(ah[i], bl[j], acc[i][j], 0, 0, 0);
        acc[i][j] = __builtin_amdgcn_mfma_f32_16x16x32_bf16(al[i], bh[j], acc[i][j], 0, 0, 0);
      }
    __syncthreads();                      // reads done before next stage
  }
}

__global__ __launch_bounds__(NTHR, 1) void kmeans_fused(
    const float* __restrict__ x, const int* __restrict__ init_idx,
    ull_t* __restrict__ cpk, float* __restrict__ cn2, int* __restrict__ ids,
    float* __restrict__ psum, float* __restrict__ pcnt,
    float* __restrict__ outp, unsigned* __restrict__ flags,
    float* __restrict__ out) {
  __shared__ s8v xhR[4096];               // 64 KB resident swizzled XH image
  __shared__ s8v xlR[4096];               // 64 KB resident swizzled XL image
  __shared__ StU u;
  __shared__ float cns[NK];
  __shared__ float redd[NK * 4];
  __shared__ int   redk[NK * 4];
  __shared__ float gmaxs[NK];
  __shared__ float labvs[NK];
  __shared__ int   labis[NK];
  __shared__ int   cntB[NK];
  __shared__ ushort_t hsm[DIM], lsm[DIM];
  __shared__ float cntsh;

  const int b = blockIdx.x;
  const int t = threadIdx.x;
  const int lane = t & 63;
  const int w  = t >> 6;
  const int wr = w >> 2, wc = w & 3;
  const int g  = lane >> 4, lr = lane & 15;
  const int pbase = b * 128;
  unsigned gen = 1;

  // ---------------- prep: own 128-pt tile -> resident hi/lo LDS image ----------------
  for (int i = 0; i < 4; ++i) {
    int G = i * NTHR + t;                 // granule [0,4096): row = pt, c = 8-dim granule
    int row = G >> 5, c = G & 31;
    const float4* src = (const float4*)(x + ((size_t)pbase + row) * DIM + c * 8);
    float4 fa = src[0], fb = src[1];
    float vv[8] = {fa.x, fa.y, fa.z, fa.w, fb.x, fb.y, fb.z, fb.w};
    s8v vh, vl;
#pragma unroll
    for (int j = 0; j < 8; ++j) {
      unsigned short hh = f2bf(vv[j]);
      vh[j] = (short)hh;
      vl[j] = (short)f2bf(vv[j] - bf2f(hh));
    }
    int pos = c ^ (row & 7);
    *(s8v*)((char*)xhR + row * 512 + pos * 16) = vh;
    *(s8v*)((char*)xlR + row * 512 + pos * 16) = vl;
  }

  // ---------------- init: c0 = x[init_idx] -> packed image + cn2 ----------------
  if (b < NK) {
    float eff = 0.f;
    if (t < DIM) {
      float v = x[init_idx[b] * DIM + t];
      unsigned short hh = f2bf(v);
      unsigned short ll = f2bf(v - bf2f(hh));
      hsm[t] = hh; lsm[t] = ll;
      eff = bf2f(hh) + bf2f(ll);
    }
    __syncthreads();
    u.c.redcn[t] = (t < DIM) ? eff * eff : 0.f;
    if (t < NK) {
      ull_t wv = (ull_t)hsm[2 * t] | ((ull_t)lsm[2 * t] << 16)
               | ((ull_t)hsm[2 * t + 1] << 32) | ((ull_t)lsm[2 * t + 1] << 48);
      cstore64(&cpk[(size_t)b * 128 + t], wv);
    }
    __syncthreads();
    for (int s = 512; s > 0; s >>= 1) { if (t < s) u.c.redcn[t] += u.c.redcn[t + s]; __syncthreads(); }
    if (t == 0) { cstore(&cn2[b * 2], u.c.redcn[0]); cstore(&cn2[b * 2 + 1], 0.f); }
  }
  gbar(flags, gen, true); ++gen;

  // ---------------- main loop: A -> B -> C, 3 clean barriers ----------------
  for (int it = 0; it < NITER; ++it) {
    // ---- phase A: assign; ids -> LLC ----
    {
      f4v acc[2][2];
      gemm_core(xhR, xlR, u, cns, t, cpk, cn2, acc);
#pragma unroll
      for (int i = 0; i < 2; ++i) {
#pragma unroll
        for (int r = 0; r < 4; ++r) {
          int prow = wr * 32 + i * 16 + g * 4 + r;
          float bd = 1e30f; int bk = 0;
#pragma unroll
          for (int j = 0; j < 2; ++j) {
            int col = wc * 32 + j * 16 + lr;
            float s = cns[col] - 2.f * acc[i][j][r];
            if (s < bd || (s == bd && col < bk)) { bd = s; bk = col; }
          }
#pragma unroll
          for (int msk = 1; msk < 16; msk <<= 1) {
            float od = __shfl_xor(bd, msk, 64);
            int   ok = __shfl_xor(bk, msk, 64);
            if (od < bd || (od == bd && ok < bk)) { bd = od; bk = ok; }
          }
          if (lr == 0) { redd[prow * 4 + wc] = bd; redk[prow * 4 + wc] = bk; }
        }
      }
      __syncthreads();
      if (t < NK) {
        float bd = redd[t * 4]; int bk = redk[t * 4];
#pragma unroll
        for (int q = 1; q < 4; ++q) {
          float dq = redd[t * 4 + q]; int kq = redk[t * 4 + q];
          if (dq < bd || (dq == bd && kq < bk)) { bd = dq; bk = kq; }
        }
        cstorei(&ids[pbase + t], bk);
      }
    }
    gbar(flags, gen, false); ++gen;

    // ---- phase B: D-split segment-sum (32 pgroups x 8 dgroups), LLC-direct x ----
    {
      const int pg = b & 31, dg = b >> 5;
      for (int i = t; i < NK * PAD; i += NTHR) u.b.accB[i] = 0.f;
      if (t < NK) cntB[t] = 0;
      u.b.idsl16[t] = (ushort_t)cloadi(&ids[pg * 1024 + t]);
      __syncthreads();
      const int id = u.b.idsl16[t];
      if (dg == 0) atomicAdd(&cntB[id], 1);
      const ull_t* xr = (const ull_t*)(x + ((size_t)pg * 1024 + t) * DIM + dg * 32);
      f4v v0 = cload128f(xr + 0),  v1 = cload128f(xr + 2);
      f4v v2 = cload128f(xr + 4),  v3 = cload128f(xr + 6);
      f4v v4 = cload128f(xr + 8),  v5 = cload128f(xr + 10);
      f4v v6 = cload128f(xr + 12), v7 = cload128f(xr + 14);
      float* ab = &u.b.accB[id * PAD];
      atomicAdd(ab + 0,  v0[0]); atomicAdd(ab + 1,  v0[1]); atomicAdd(ab + 2,  v0[2]); atomicAdd(ab + 3,  v0[3]);
      atomicAdd(ab + 4,  v1[0]); atomicAdd(ab + 5,  v1[1]); atomicAdd(ab + 6,  v1[2]); atomicAdd(ab + 7,  v1[3]);
      atomicAdd(ab + 8,  v2[0]); atomicAdd(ab + 9,  v2[1]); atomicAdd(ab + 10, v2[2]); atomicAdd(ab + 11, v2[3]);
      atomicAdd(ab + 12, v3[0]); atomicAdd(ab + 13, v3[1]); atomicAdd(ab + 14, v3[2]); atomicAdd(ab + 15, v3[3]);
      atomicAdd(ab + 16, v4[0]); atomicAdd(ab + 17, v4[1]); atomicAdd(ab + 18, v4[2]); atomicAdd(ab + 19, v4[3]);
      atomicAdd(ab + 20, v5[0]); atomicAdd(ab + 21, v5[1]); atomicAdd(ab + 22, v5[2]); atomicAdd(ab + 23, v5[3]);
      atomicAdd(ab + 24, v6[0]); atomicAdd(ab + 25, v6[1]); atomicAdd(ab + 26, v6[2]); atomicAdd(ab + 27, v6[3]);
      atomicAdd(ab + 28, v7[0]); atomicAdd(ab + 29, v7[1]); atomicAdd(ab + 30, v7[2]); atomicAdd(ab + 31, v7[3]);
      __syncthreads();
#pragma unroll
      for (int s2 = 0; s2 < 4; ++s2) {
        int idx = s2 * NTHR + t;          // [0,4096)
        int k2 = idx >> 5, dl = idx & 31;
        cstore(&psum[(((size_t)dg * NK + k2) * 32 + pg) * 32 + dl], u.b.accB[k2 * PAD + dl]);
      }
      if (dg == 0 && t < NK)
        cstore(&pcnt[(size_t)pg * NK + t], (float)cntB[t]);
    }
    gbar(flags, gen, false); ++gen;

    // ---- phase C: 256 blocks = 128 clusters x 2 D-halves ----
    {
      const int k = b >> 1, hh2 = b & 1;
      const int dwh = t & 127, pch = t >> 7;   // dim-in-half [0,128), pgroup chunk [0,8)
      const int dgc = hh2 * 4 + (dwh >> 5), dlc = dwh & 31;
      float s = 0.f;
#pragma unroll
      for (int p2 = pch * 4; p2 < pch * 4 + 4; ++p2)
        s += cload(&psum[(((size_t)dgc * NK + k) * 32 + p2) * 32 + dlc]);
      u.c.red4[pch * 128 + dwh] = s;
      float cv = (t < 32) ? cload(&pcnt[(size_t)t * NK + k]) : 0.f;
      if (t < 64) {
#pragma unroll
        for (int m = 1; m < 32; m <<= 1) cv += __shfl_xor(cv, m, 64);
      }
      if (t == 0) cntsh = cv;
      __syncthreads();
      float eff = 0.f;
      if (t < 128) {
        float ssum = 0.f;
#pragma unroll
        for (int ww = 0; ww < 8; ++ww) ssum += u.c.red4[ww * 128 + t];
        float mean = ssum / cntsh;        // NaN if empty, as ref
        unsigned short hh = f2bf(mean);
        unsigned short ll = f2bf(mean - bf2f(hh));
        hsm[t] = hh; lsm[t] = ll;
        eff = bf2f(hh) + bf2f(ll);
      }
      __syncthreads();                    // red4 reads + hsm/lsm writes done
      u.c.redcn[t] = (t < 128) ? eff * eff : 0.f;
      if (t < 64) {
        ull_t wv = (ull_t)hsm[2 * t] | ((ull_t)lsm[2 * t] << 16)
                 | ((ull_t)hsm[2 * t + 1] << 32) | ((ull_t)lsm[2 * t + 1] << 48);
        cstore64(&cpk[(size_t)k * 128 + hh2 * 64 + t], wv);
      }
      __syncthreads();
      for (int st = 512; st > 0; st >>= 1) { if (t < st) u.c.redcn[t] += u.c.redcn[t + st]; __syncthreads(); }
      if (t == 0) cstore(&cn2[k * 2 + hh2], u.c.redcn[0]);
    }
    gbar(flags, gen, true); ++gen;        // acquire fence: fresh cpk for A's normal loads
  }

  // ---------------- final: loss (log-softmax + CE), deterministic reduce ----------------
  {
    f4v acc[2][2];
    gemm_core(xhR, xlR, u, cns, t, cpk, cn2, acc);
#pragma unroll
    for (int i = 0; i < 2; ++i) {
#pragma unroll
      for (int r = 0; r < 4; ++r) {
        int prow = wr * 32 + i * 16 + g * 4 + r;
        float m = -1e30f;
#pragma unroll
        for (int j = 0; j < 2; ++j) m = fmaxf(m, acc[i][j][r]);
#pragma unroll
        for (int msk = 1; msk < 16; msk <<= 1) m = fmaxf(m, __shfl_xor(m, msk, 64));
        if (lr == 0) redd[prow * 4 + wc] = m;
      }
    }
    __syncthreads();
    if (t < NK) {
      float m = redd[t * 4];
#pragma unroll
      for (int q = 1; q < 4; ++q) m = fmaxf(m, redd[t * 4 + q]);
      gmaxs[t] = m;
      labis[t] = cloadi(&ids[pbase + t]);
    }
    __syncthreads();
#pragma unroll
    for (int i = 0; i < 2; ++i) {
#pragma unroll
      for (int r = 0; r < 4; ++r) {
        int prow = wr * 32 + i * 16 + g * 4 + r;
        float m = gmaxs[prow];
        int lab = labis[prow];
        float s = 0.f;
#pragma unroll
        for (int j = 0; j < 2; ++j) {
          int col = wc * 32 + j * 16 + lr;
          float v = acc[i][j][r];
          s += expf(v - m);
          if (col == lab) labvs[prow] = v;
        }
#pragma unroll
        for (int msk = 1; msk < 16; msk <<= 1) s += __shfl_xor(s, msk, 64);
        if (lr == 0) redd[prow * 4 + wc] = s;
      }
    }
    __syncthreads();
    if (t < NK) {
      float se = redd[t * 4] + redd[t * 4 + 1] + redd[t * 4 + 2] + redd[t * 4 + 3];
      float lse = gmaxs[t] + logf(se);
      gmaxs[t] = lse - labvs[t];
    }
    __syncthreads();
    if (t == 0) {
      float tot = 0.f;
      for (int q = 0; q < NK; ++q) tot += gmaxs[q];
      cstore(&outp[b], tot);
    }
  }
  gbar(flags, gen, false); ++gen;
  if (b == 0) {
    u.c.redcn[t] = (t < NBLK) ? cload(&outp[t]) : 0.f;
    __syncthreads();
    for (int s = 512; s > 0; s >>= 1) { if (t < s) u.c.redcn[t] += u.c.redcn[t + s]; __syncthreads(); }
    if (t == 0) out[0] = u.c.redcn[0] * (1.0f / (float)NPTS);
  }
}

extern "C" void kernel_launch(void* const* d_in, const int* in_sizes, int n_in,
                              void* d_out, int out_size, void* d_ws, size_t ws_size,
                              hipStream_t stream) {
  const float* x        = (const float*)d_in[0];
  const int*   init_idx = (const int*)d_in[1];
  float* out = (float*)d_out;
  char* ws = (char*)d_ws;

  // ws layout (bytes):
  ull_t* cpk  = (ull_t*)(ws);                         // 128*128*8 = 131072
  float* cn2  = (float*)(ws + 131072);                // 1024
  int*   ids  = (int*)(ws + 132096);                  // 131072
  float* psum = (float*)(ws + 263168);                // 8*128*32*32*4 = 4194304
  float* pcnt = (float*)(ws + 4457472);               // 32*128*4 = 16384
  float* outp = (float*)(ws + 4473856);               // 1024
  unsigned* flags = (unsigned*)(ws + 4474880);        // 256*64B = 16384

  // reset barrier state every launch (graph replays include this node)
  hipMemsetAsync(flags, 0, 16384, stream);
  kmeans_fused<<<dim3(NBLK), dim3(NTHR), 0, stream>>>(
      x, init_idx, cpk, cn2, ids, psum, pcnt, outp, flags, out);
}

// Round 14
// 7191.567 us; speedup vs baseline: 1.3566x; 1.0476x over previous
//
#include <hip/hip_runtime.h>
#include <cstdint>

#define NPTS 32768
#define DIM  256
#define NK   128
#define NITER 100
#define NBLK 256
#define NTHR 1024
#define PAD  33

typedef unsigned short ushort_t;
typedef unsigned long long ull_t;
typedef __attribute__((ext_vector_type(8))) short s8v;   // 8 bf16 in 4 VGPRs
typedef __attribute__((ext_vector_type(4))) float f4v;   // MFMA accumulator

__device__ __forceinline__ unsigned short f2bf(float f) {
  unsigned u = __float_as_uint(f);
  u += 0x7fffu + ((u >> 16) & 1u);      // RTNE
  return (unsigned short)(u >> 16);
}
__device__ __forceinline__ float bf2f(unsigned short b) {
  return __uint_as_float(((unsigned)b) << 16);
}

// agent-scope (LLC-coherent) accesses — bypass non-coherent L1/L2
__device__ __forceinline__ void cstore(float* p, float v) {
  __hip_atomic_store(p, v, __ATOMIC_RELAXED, __HIP_MEMORY_SCOPE_AGENT);
}
__device__ __forceinline__ float cload(const float* p) {
  return __hip_atomic_load(p, __ATOMIC_RELAXED, __HIP_MEMORY_SCOPE_AGENT);
}
__device__ __forceinline__ void cstorei(int* p, int v) {
  __hip_atomic_store(p, v, __ATOMIC_RELAXED, __HIP_MEMORY_SCOPE_AGENT);
}
__device__ __forceinline__ int cloadi(const int* p) {
  return __hip_atomic_load(p, __ATOMIC_RELAXED, __HIP_MEMORY_SCOPE_AGENT);
}
__device__ __forceinline__ void cstore64(ull_t* p, ull_t v) {
  __hip_atomic_store(p, v, __ATOMIC_RELAXED, __HIP_MEMORY_SCOPE_AGENT);
}
__device__ __forceinline__ f4v cload128f(const ull_t* p) {
  ull_t a = __hip_atomic_load(p, __ATOMIC_RELAXED, __HIP_MEMORY_SCOPE_AGENT);
  ull_t b = __hip_atomic_load(p + 1, __ATOMIC_RELAXED, __HIP_MEMORY_SCOPE_AGENT);
  f4v r;
  r[0] = __uint_as_float((unsigned)a); r[1] = __uint_as_float((unsigned)(a >> 32));
  r[2] = __uint_as_float((unsigned)b); r[3] = __uint_as_float((unsigned)(b >> 32));
  return r;
}

// ---- aggregated 2-hop grid barrier, fence-free, low poll traffic ----
// Hop 1: each block's leader stores its padded flag (parallel, no RMW).
// Hop 2: ONLY block 0 polls the 256 flags (1 thread per flag), then publishes
// to 64 replicated generation words; every other block polls ONE word with
// ONE lane. Poll traffic ~1000x lower than all-to-all (no LLC DDoS on the
// tail blocks' phase-ending stores).
// inv=true: acquire __threadfence after release so subsequent NORMAL loads
// (cpk staging in gemm_core) see agent-scope writes.
__device__ __forceinline__ void gbar(unsigned* flags, unsigned* grep, unsigned gen, bool inv) {
  __syncthreads();                        // drain all vmem (cstores visible)
  if (threadIdx.x == 0)
    __hip_atomic_store(&flags[blockIdx.x * 16], gen, __ATOMIC_RELAXED, __HIP_MEMORY_SCOPE_AGENT);
  if (blockIdx.x == 0) {
    if (threadIdx.x < NBLK) {
      while (__hip_atomic_load(&flags[threadIdx.x * 16], __ATOMIC_RELAXED, __HIP_MEMORY_SCOPE_AGENT) < gen)
        __builtin_amdgcn_s_sleep(2);
    }
    __syncthreads();                      // all 256 arrivals observed
    if (threadIdx.x < 64)
      __hip_atomic_store(&grep[threadIdx.x * 16], gen, __ATOMIC_RELAXED, __HIP_MEMORY_SCOPE_AGENT);
  }
  if (threadIdx.x == 0) {
    while (__hip_atomic_load(&grep[(blockIdx.x & 63) * 16], __ATOMIC_RELAXED, __HIP_MEMORY_SCOPE_AGENT) < gen)
      __builtin_amdgcn_s_sleep(2);
  }
  __syncthreads();
  if (inv && threadIdx.x == 0) __threadfence();
  asm volatile("" ::: "memory");
  __syncthreads();
}

union StU {                 // phase-exclusive LDS scratch (20.5 KB)
  struct { char ch[128 * 80]; char cl[128 * 80]; } a;       // GEMM C-eighth tiles (padded rows)
  struct { float accB[NK * PAD]; ushort_t idsl16[1024]; } b;
  struct { float red4[1024]; float redcn[1024]; } c;
};

// 16-wave (4x4) 3-pass hi/lo bf16 MFMA GEMM over 8 D-eighths (32 dims each).
// A-operand: resident swizzled LDS x-image. B-operand: cpk staged per eighth
// via NORMAL loads (L2-shared per XCD; freshness via C->A acquire fence).
__device__ __forceinline__ void gemm_core(
    const s8v* __restrict__ xhR, const s8v* __restrict__ xlR,
    StU& u, float* cns, int t,
    const ull_t* __restrict__ cpk, const float* __restrict__ cn2, f4v (&acc)[2][2]) {
  const int lane = t & 63;
  const int w    = t >> 6;
  const int wr   = w >> 2, wc = w & 3;    // 4x4 wave grid
  const int g    = lane >> 4, lr = lane & 15;

  if (t < NK) cns[t] = cload(&cn2[2 * t]) + cload(&cn2[2 * t + 1]);

  const f4v zero = {0.f, 0.f, 0.f, 0.f};
#pragma unroll
  for (int i = 0; i < 2; ++i)
#pragma unroll
    for (int j = 0; j < 2; ++j) acc[i][j] = zero;

  for (int q = 0; q < 8; ++q) {           // eighths: dims q*32..q*32+31
    if (t < 512) {                        // stage CH/CL eighth (normal loads)
      int row = t >> 2, c = t & 3;        // row=cluster, c=granule (8 dims)
      const ull_t* src = cpk + (size_t)row * 128 + q * 16 + c * 4;
      ull_t w0 = src[0], w1 = src[1], w2 = src[2], w3 = src[3];
      s8v vh, vl;
      vh[0] = (short)w0; vl[0] = (short)(w0 >> 16); vh[1] = (short)(w0 >> 32); vl[1] = (short)(w0 >> 48);
      vh[2] = (short)w1; vl[2] = (short)(w1 >> 16); vh[3] = (short)(w1 >> 32); vl[3] = (short)(w1 >> 48);
      vh[4] = (short)w2; vl[4] = (short)(w2 >> 16); vh[5] = (short)(w2 >> 32); vl[5] = (short)(w2 >> 48);
      vh[6] = (short)w3; vl[6] = (short)(w3 >> 16); vh[7] = (short)(w3 >> 32); vl[7] = (short)(w3 >> 48);
      *(s8v*)(u.a.ch + row * 80 + c * 16) = vh;
      *(s8v*)(u.a.cl + row * 80 + c * 16) = vl;
    }
    __syncthreads();                      // stage landed; prev eighth reads done
    s8v ah[2], al[2], bh[2], bl[2];
#pragma unroll
    for (int i = 0; i < 2; ++i) {
      int ra = wr * 32 + i * 16 + lr;
      int o = ra * 512 + (((q * 4 + g) ^ (lr & 7)) * 16);
      ah[i] = *(const s8v*)((const char*)xhR + o);
      al[i] = *(const s8v*)((const char*)xlR + o);
    }
#pragma unroll
    for (int j = 0; j < 2; ++j) {
      int rb = wc * 32 + j * 16 + lr;
      int o = rb * 80 + g * 16;
      bh[j] = *(const s8v*)(u.a.ch + o);
      bl[j] = *(const s8v*)(u.a.cl + o);
    }
#pragma unroll
    for (int i = 0; i < 2; ++i)
#pragma unroll
      for (int j = 0; j < 2; ++j) {
        acc[i][j] = __builtin_amdgcn_mfma_f32_16x16x32_bf16(ah[i], bh[j], acc[i][j], 0, 0, 0);
        acc[i][j] = __builtin_amdgcn_mfma_f32_16x16x32_bf16(ah[i], bl[j], acc[i][j], 0, 0, 0);
        acc[i][j] = __builtin_amdgcn_mfma_f32_16x16x32_bf16(al[i], bh[j], acc[i][j], 0, 0, 0);
      }
    __syncthreads();                      // reads done before next stage
  }
}

__global__ __launch_bounds__(NTHR, 1) void kmeans_fused(
    const float* __restrict__ x, const int* __restrict__ init_idx,
    ull_t* __restrict__ cpk, float* __restrict__ cn2, int* __restrict__ ids,
    float* __restrict__ psum, float* __restrict__ pcnt,
    float* __restrict__ outp, unsigned* __restrict__ flags,
    unsigned* __restrict__ grep, float* __restrict__ out) {
  __shared__ s8v xhR[4096];               // 64 KB resident swizzled XH image
  __shared__ s8v xlR[4096];               // 64 KB resident swizzled XL image
  __shared__ StU u;
  __shared__ float cns[NK];
  __shared__ float redd[NK * 4];
  __shared__ int   redk[NK * 4];
  __shared__ float gmaxs[NK];
  __shared__ float labvs[NK];
  __shared__ int   labis[NK];
  __shared__ int   cntB[NK];
  __shared__ ushort_t hsm[DIM], lsm[DIM];
  __shared__ float cntsh;

  const int b = blockIdx.x;
  const int t = threadIdx.x;
  const int lane = t & 63;
  const int w  = t >> 6;
  const int wr = w >> 2, wc = w & 3;
  const int g  = lane >> 4, lr = lane & 15;
  const int pbase = b * 128;
  unsigned gen = 1;

  // ---------------- prep: own 128-pt tile -> resident hi/lo LDS image ----------------
  for (int i = 0; i < 4; ++i) {
    int G = i * NTHR + t;                 // granule [0,4096): row = pt, c = 8-dim granule
    int row = G >> 5, c = G & 31;
    const float4* src = (const float4*)(x + ((size_t)pbase + row) * DIM + c * 8);
    float4 fa = src[0], fb = src[1];
    float vv[8] = {fa.x, fa.y, fa.z, fa.w, fb.x, fb.y, fb.z, fb.w};
    s8v vh, vl;
#pragma unroll
    for (int j = 0; j < 8; ++j) {
      unsigned short hh = f2bf(vv[j]);
      vh[j] = (short)hh;
      vl[j] = (short)f2bf(vv[j] - bf2f(hh));
    }
    int pos = c ^ (row & 7);
    *(s8v*)((char*)xhR + row * 512 + pos * 16) = vh;
    *(s8v*)((char*)xlR + row * 512 + pos * 16) = vl;
  }

  // ---------------- init: c0 = x[init_idx] -> packed image + cn2 ----------------
  if (b < NK) {
    float eff = 0.f;
    if (t < DIM) {
      float v = x[init_idx[b] * DIM + t];
      unsigned short hh = f2bf(v);
      unsigned short ll = f2bf(v - bf2f(hh));
      hsm[t] = hh; lsm[t] = ll;
      eff = bf2f(hh) + bf2f(ll);
    }
    __syncthreads();
    u.c.redcn[t] = (t < DIM) ? eff * eff : 0.f;
    if (t < NK) {
      ull_t wv = (ull_t)hsm[2 * t] | ((ull_t)lsm[2 * t] << 16)
               | ((ull_t)hsm[2 * t + 1] << 32) | ((ull_t)lsm[2 * t + 1] << 48);
      cstore64(&cpk[(size_t)b * 128 + t], wv);
    }
    __syncthreads();
    for (int s = 512; s > 0; s >>= 1) { if (t < s) u.c.redcn[t] += u.c.redcn[t + s]; __syncthreads(); }
    if (t == 0) { cstore(&cn2[b * 2], u.c.redcn[0]); cstore(&cn2[b * 2 + 1], 0.f); }
  }
  gbar(flags, grep, gen, true); ++gen;

  // ---------------- main loop: A -> B -> C ----------------
  for (int it = 0; it < NITER; ++it) {
    // ---- phase A: assign; ids -> LLC ----
    {
      f4v acc[2][2];
      gemm_core(xhR, xlR, u, cns, t, cpk, cn2, acc);
#pragma unroll
      for (int i = 0; i < 2; ++i) {
#pragma unroll
        for (int r = 0; r < 4; ++r) {
          int prow = wr * 32 + i * 16 + g * 4 + r;
          float bd = 1e30f; int bk = 0;
#pragma unroll
          for (int j = 0; j < 2; ++j) {
            int col = wc * 32 + j * 16 + lr;
            float s = cns[col] - 2.f * acc[i][j][r];
            if (s < bd || (s == bd && col < bk)) { bd = s; bk = col; }
          }
#pragma unroll
          for (int msk = 1; msk < 16; msk <<= 1) {
            float od = __shfl_xor(bd, msk, 64);
            int   ok = __shfl_xor(bk, msk, 64);
            if (od < bd || (od == bd && ok < bk)) { bd = od; bk = ok; }
          }
          if (lr == 0) { redd[prow * 4 + wc] = bd; redk[prow * 4 + wc] = bk; }
        }
      }
      __syncthreads();
      if (t < NK) {
        float bd = redd[t * 4]; int bk = redk[t * 4];
#pragma unroll
        for (int q = 1; q < 4; ++q) {
          float dq = redd[t * 4 + q]; int kq = redk[t * 4 + q];
          if (dq < bd || (dq == bd && kq < bk)) { bd = dq; bk = kq; }
        }
        cstorei(&ids[pbase + t], bk);
      }
    }
    gbar(flags, grep, gen, false); ++gen;

    // ---- phase B: D-split segment-sum (32 pgroups x 8 dgroups), LLC-direct x ----
    {
      const int pg = b & 31, dg = b >> 5;
      for (int i = t; i < NK * PAD; i += NTHR) u.b.accB[i] = 0.f;
      if (t < NK) cntB[t] = 0;
      u.b.idsl16[t] = (ushort_t)cloadi(&ids[pg * 1024 + t]);
      __syncthreads();
      const int id = u.b.idsl16[t];
      if (dg == 0) atomicAdd(&cntB[id], 1);
      const ull_t* xr = (const ull_t*)(x + ((size_t)pg * 1024 + t) * DIM + dg * 32);
      f4v v0 = cload128f(xr + 0),  v1 = cload128f(xr + 2);
      f4v v2 = cload128f(xr + 4),  v3 = cload128f(xr + 6);
      f4v v4 = cload128f(xr + 8),  v5 = cload128f(xr + 10);
      f4v v6 = cload128f(xr + 12), v7 = cload128f(xr + 14);
      float* ab = &u.b.accB[id * PAD];
      atomicAdd(ab + 0,  v0[0]); atomicAdd(ab + 1,  v0[1]); atomicAdd(ab + 2,  v0[2]); atomicAdd(ab + 3,  v0[3]);
      atomicAdd(ab + 4,  v1[0]); atomicAdd(ab + 5,  v1[1]); atomicAdd(ab + 6,  v1[2]); atomicAdd(ab + 7,  v1[3]);
      atomicAdd(ab + 8,  v2[0]); atomicAdd(ab + 9,  v2[1]); atomicAdd(ab + 10, v2[2]); atomicAdd(ab + 11, v2[3]);
      atomicAdd(ab + 12, v3[0]); atomicAdd(ab + 13, v3[1]); atomicAdd(ab + 14, v3[2]); atomicAdd(ab + 15, v3[3]);
      atomicAdd(ab + 16, v4[0]); atomicAdd(ab + 17, v4[1]); atomicAdd(ab + 18, v4[2]); atomicAdd(ab + 19, v4[3]);
      atomicAdd(ab + 20, v5[0]); atomicAdd(ab + 21, v5[1]); atomicAdd(ab + 22, v5[2]); atomicAdd(ab + 23, v5[3]);
      atomicAdd(ab + 24, v6[0]); atomicAdd(ab + 25, v6[1]); atomicAdd(ab + 26, v6[2]); atomicAdd(ab + 27, v6[3]);
      atomicAdd(ab + 28, v7[0]); atomicAdd(ab + 29, v7[1]); atomicAdd(ab + 30, v7[2]); atomicAdd(ab + 31, v7[3]);
      __syncthreads();
#pragma unroll
      for (int s2 = 0; s2 < 4; ++s2) {
        int idx = s2 * NTHR + t;          // [0,4096)
        int k2 = idx >> 5, dl = idx & 31;
        cstore(&psum[(((size_t)dg * NK + k2) * 32 + pg) * 32 + dl], u.b.accB[k2 * PAD + dl]);
      }
      if (dg == 0 && t < NK)
        cstore(&pcnt[(size_t)pg * NK + t], (float)cntB[t]);
    }
    gbar(flags, grep, gen, false); ++gen;

    // ---- phase C: 256 blocks = 128 clusters x 2 D-halves ----
    {
      const int k = b >> 1, hh2 = b & 1;
      const int dwh = t & 127, pch = t >> 7;   // dim-in-half [0,128), pgroup chunk [0,8)
      const int dgc = hh2 * 4 + (dwh >> 5), dlc = dwh & 31;
      float s = 0.f;
#pragma unroll
      for (int p2 = pch * 4; p2 < pch * 4 + 4; ++p2)
        s += cload(&psum[(((size_t)dgc * NK + k) * 32 + p2) * 32 + dlc]);
      u.c.red4[pch * 128 + dwh] = s;
      float cv = (t < 32) ? cload(&pcnt[(size_t)t * NK + k]) : 0.f;
      if (t < 64) {
#pragma unroll
        for (int m = 1; m < 32; m <<= 1) cv += __shfl_xor(cv, m, 64);
      }
      if (t == 0) cntsh = cv;
      __syncthreads();
      float eff = 0.f;
      if (t < 128) {
        float ssum = 0.f;
#pragma unroll
        for (int ww = 0; ww < 8; ++ww) ssum += u.c.red4[ww * 128 + t];
        float mean = ssum / cntsh;        // NaN if empty, as ref
        unsigned short hh = f2bf(mean);
        unsigned short ll = f2bf(mean - bf2f(hh));
        hsm[t] = hh; lsm[t] = ll;
        eff = bf2f(hh) + bf2f(ll);
      }
      __syncthreads();                    // red4 reads + hsm/lsm writes done
      u.c.redcn[t] = (t < 128) ? eff * eff : 0.f;
      if (t < 64) {
        ull_t wv = (ull_t)hsm[2 * t] | ((ull_t)lsm[2 * t] << 16)
                 | ((ull_t)hsm[2 * t + 1] << 32) | ((ull_t)lsm[2 * t + 1] << 48);
        cstore64(&cpk[(size_t)k * 128 + hh2 * 64 + t], wv);
      }
      __syncthreads();
      for (int st = 512; st > 0; st >>= 1) { if (t < st) u.c.redcn[t] += u.c.redcn[t + st]; __syncthreads(); }
      if (t == 0) cstore(&cn2[k * 2 + hh2], u.c.redcn[0]);
    }
    gbar(flags, grep, gen, true); ++gen;  // acquire fence: fresh cpk for A's normal loads
  }

  // ---------------- final: loss (log-softmax + CE), deterministic reduce ----------------
  {
    f4v acc[2][2];
    gemm_core(xhR, xlR, u, cns, t, cpk, cn2, acc);
#pragma unroll
    for (int i = 0; i < 2; ++i) {
#pragma unroll
      for (int r = 0; r < 4; ++r) {
        int prow = wr * 32 + i * 16 + g * 4 + r;
        float m = -1e30f;
#pragma unroll
        for (int j = 0; j < 2; ++j) m = fmaxf(m, acc[i][j][r]);
#pragma unroll
        for (int msk = 1; msk < 16; msk <<= 1) m = fmaxf(m, __shfl_xor(m, msk, 64));
        if (lr == 0) redd[prow * 4 + wc] = m;
      }
    }
    __syncthreads();
    if (t < NK) {
      float m = redd[t * 4];
#pragma unroll
      for (int q = 1; q < 4; ++q) m = fmaxf(m, redd[t * 4 + q]);
      gmaxs[t] = m;
      labis[t] = cloadi(&ids[pbase + t]);
    }
    __syncthreads();
#pragma unroll
    for (int i = 0; i < 2; ++i) {
#pragma unroll
      for (int r = 0; r < 4; ++r) {
        int prow = wr * 32 + i * 16 + g * 4 + r;
        float m = gmaxs[prow];
        int lab = labis[prow];
        float s = 0.f;
#pragma unroll
        for (int j = 0; j < 2; ++j) {
          int col = wc * 32 + j * 16 + lr;
          float v = acc[i][j][r];
          s += expf(v - m);
          if (col == lab) labvs[prow] = v;
        }
#pragma unroll
        for (int msk = 1; msk < 16; msk <<= 1) s += __shfl_xor(s, msk, 64);
        if (lr == 0) redd[prow * 4 + wc] = s;
      }
    }
    __syncthreads();
    if (t < NK) {
      float se = redd[t * 4] + redd[t * 4 + 1] + redd[t * 4 + 2] + redd[t * 4 + 3];
      float lse = gmaxs[t] + logf(se);
      gmaxs[t] = lse - labvs[t];
    }
    __syncthreads();
    if (t == 0) {
      float tot = 0.f;
      for (int q = 0; q < NK; ++q) tot += gmaxs[q];
      cstore(&outp[b], tot);
    }
  }
  gbar(flags, grep, gen, false); ++gen;
  if (b == 0) {
    u.c.redcn[t] = (t < NBLK) ? cload(&outp[t]) : 0.f;
    __syncthreads();
    for (int s = 512; s > 0; s >>= 1) { if (t < s) u.c.redcn[t] += u.c.redcn[t + s]; __syncthreads(); }
    if (t == 0) out[0] = u.c.redcn[0] * (1.0f / (float)NPTS);
  }
}

extern "C" void kernel_launch(void* const* d_in, const int* in_sizes, int n_in,
                              void* d_out, int out_size, void* d_ws, size_t ws_size,
                              hipStream_t stream) {
  const float* x        = (const float*)d_in[0];
  const int*   init_idx = (const int*)d_in[1];
  float* out = (float*)d_out;
  char* ws = (char*)d_ws;

  // ws layout (bytes):
  ull_t* cpk  = (ull_t*)(ws);                         // 128*128*8 = 131072
  float* cn2  = (float*)(ws + 131072);                // 1024
  int*   ids  = (int*)(ws + 132096);                  // 131072
  float* psum = (float*)(ws + 263168);                // 8*128*32*32*4 = 4194304
  float* pcnt = (float*)(ws + 4457472);               // 32*128*4 = 16384
  float* outp = (float*)(ws + 4473856);               // 1024
  unsigned* flags = (unsigned*)(ws + 4474880);        // 256*64B = 16384
  unsigned* grep  = (unsigned*)(ws + 4491264);        // 64*64B = 4096

  // reset barrier state every launch (graph replays include this node)
  hipMemsetAsync(flags, 0, 20480, stream);
  kmeans_fused<<<dim3(NBLK), dim3(NTHR), 0, stream>>>(
      x, init_idx, cpk, cn2, ids, psum, pcnt, outp, flags, grep, out);
}

// Round 15
// 6855.064 us; speedup vs baseline: 1.4231x; 1.0491x over previous
//
#include <hip/hip_runtime.h>
#include <cstdint>

#define NPTS 32768
#define DIM  256
#define NK   128
#define NITER 100
#define NBLK 256
#define NTHR 1024
#define PAD  33

typedef unsigned short ushort_t;
typedef unsigned long long ull_t;
typedef __attribute__((ext_vector_type(8))) short s8v;   // 8 bf16 in 4 VGPRs
typedef __attribute__((ext_vector_type(4))) float f4v;   // MFMA accumulator

__device__ __forceinline__ unsigned short f2bf(float f) {
  unsigned u = __float_as_uint(f);
  u += 0x7fffu + ((u >> 16) & 1u);      // RTNE
  return (unsigned short)(u >> 16);
}
__device__ __forceinline__ float bf2f(unsigned short b) {
  return __uint_as_float(((unsigned)b) << 16);
}

// agent-scope (LLC-coherent) accesses — bypass non-coherent L1/L2
__device__ __forceinline__ void cstore(float* p, float v) {
  __hip_atomic_store(p, v, __ATOMIC_RELAXED, __HIP_MEMORY_SCOPE_AGENT);
}
__device__ __forceinline__ float cload(const float* p) {
  return __hip_atomic_load(p, __ATOMIC_RELAXED, __HIP_MEMORY_SCOPE_AGENT);
}
__device__ __forceinline__ void cstorei(int* p, int v) {
  __hip_atomic_store(p, v, __ATOMIC_RELAXED, __HIP_MEMORY_SCOPE_AGENT);
}
__device__ __forceinline__ int cloadi(const int* p) {
  return __hip_atomic_load(p, __ATOMIC_RELAXED, __HIP_MEMORY_SCOPE_AGENT);
}
__device__ __forceinline__ void cstore64(ull_t* p, ull_t v) {
  __hip_atomic_store(p, v, __ATOMIC_RELAXED, __HIP_MEMORY_SCOPE_AGENT);
}

// ---- aggregated 2-hop grid barrier, fence-free (proven R14) ----
__device__ __forceinline__ void gbar(unsigned* flags, unsigned* grep, unsigned gen) {
  __syncthreads();                        // drain all vmem (cstores visible)
  if (threadIdx.x == 0)
    __hip_atomic_store(&flags[blockIdx.x * 16], gen, __ATOMIC_RELAXED, __HIP_MEMORY_SCOPE_AGENT);
  if (blockIdx.x == 0) {
    if (threadIdx.x < NBLK) {
      while (__hip_atomic_load(&flags[threadIdx.x * 16], __ATOMIC_RELAXED, __HIP_MEMORY_SCOPE_AGENT) < gen)
        __builtin_amdgcn_s_sleep(2);
    }
    __syncthreads();                      // all 256 arrivals observed
    if (threadIdx.x < 64)
      __hip_atomic_store(&grep[threadIdx.x * 16], gen, __ATOMIC_RELAXED, __HIP_MEMORY_SCOPE_AGENT);
  }
  if (threadIdx.x == 0) {
    while (__hip_atomic_load(&grep[(blockIdx.x & 63) * 16], __ATOMIC_RELAXED, __HIP_MEMORY_SCOPE_AGENT) < gen)
      __builtin_amdgcn_s_sleep(2);
  }
  __syncthreads();
  asm volatile("" ::: "memory");
  __syncthreads();
}

union StU {                 // phase-exclusive LDS scratch (20.5 KB)
  struct { char ch[128 * 80]; char cl[128 * 80]; } a;       // GEMM C-eighth tiles (padded rows)
  struct { float accB[NK * PAD]; ushort_t idsl16[1024]; } b;
  struct { float red4[1024]; float redcn[1024]; } c;
};

// 16-wave (4x4) 3-pass hi/lo bf16 MFMA GEMM over 8 D-eighths (32 dims each).
// A-operand: resident swizzled LDS x-image. B-operand: VERSIONED cpk staged
// per eighth via NORMAL loads — fresh addresses every iteration, so no stale
// L2 lines and no fences needed.
__device__ __forceinline__ void gemm_core(
    const s8v* __restrict__ xhR, const s8v* __restrict__ xlR,
    StU& u, float* cns, int t,
    const ull_t* __restrict__ cpk, const float* __restrict__ cn2, f4v (&acc)[2][2]) {
  const int lane = t & 63;
  const int w    = t >> 6;
  const int wr   = w >> 2, wc = w & 3;    // 4x4 wave grid
  const int g    = lane >> 4, lr = lane & 15;

  if (t < NK) cns[t] = cload(&cn2[2 * t]) + cload(&cn2[2 * t + 1]);

  const f4v zero = {0.f, 0.f, 0.f, 0.f};
#pragma unroll
  for (int i = 0; i < 2; ++i)
#pragma unroll
    for (int j = 0; j < 2; ++j) acc[i][j] = zero;

  for (int q = 0; q < 8; ++q) {           // eighths: dims q*32..q*32+31
    if (t < 512) {                        // stage CH/CL eighth (normal loads)
      int row = t >> 2, c = t & 3;        // row=cluster, c=granule (8 dims)
      const ull_t* src = cpk + (size_t)row * 128 + q * 16 + c * 4;
      ull_t w0 = src[0], w1 = src[1], w2 = src[2], w3 = src[3];
      s8v vh, vl;
      vh[0] = (short)w0; vl[0] = (short)(w0 >> 16); vh[1] = (short)(w0 >> 32); vl[1] = (short)(w0 >> 48);
      vh[2] = (short)w1; vl[2] = (short)(w1 >> 16); vh[3] = (short)(w1 >> 32); vl[3] = (short)(w1 >> 48);
      vh[4] = (short)w2; vl[4] = (short)(w2 >> 16); vh[5] = (short)(w2 >> 32); vl[5] = (short)(w2 >> 48);
      vh[6] = (short)w3; vl[6] = (short)(w3 >> 16); vh[7] = (short)(w3 >> 32); vl[7] = (short)(w3 >> 48);
      *(s8v*)(u.a.ch + row * 80 + c * 16) = vh;
      *(s8v*)(u.a.cl + row * 80 + c * 16) = vl;
    }
    __syncthreads();                      // stage landed; prev eighth reads done
    s8v ah[2], al[2], bh[2], bl[2];
#pragma unroll
    for (int i = 0; i < 2; ++i) {
      int ra = wr * 32 + i * 16 + lr;
      int o = ra * 512 + (((q * 4 + g) ^ (lr & 7)) * 16);
      ah[i] = *(const s8v*)((const char*)xhR + o);
      al[i] = *(const s8v*)((const char*)xlR + o);
    }
#pragma unroll
    for (int j = 0; j < 2; ++j) {
      int rb = wc * 32 + j * 16 + lr;
      int o = rb * 80 + g * 16;
      bh[j] = *(const s8v*)(u.a.ch + o);
      bl[j] = *(const s8v*)(u.a.cl + o);
    }
#pragma unroll
    for (int i = 0; i < 2; ++i)
#pragma unroll
      for (int j = 0; j < 2; ++j) {
        acc[i][j] = __builtin_amdgcn_mfma_f32_16x16x32_bf16(ah[i], bh[j], acc[i][j], 0, 0, 0);
        acc[i][j] = __builtin_amdgcn_mfma_f32_16x16x32_bf16(ah[i], bl[j], acc[i][j], 0, 0, 0);
        acc[i][j] = __builtin_amdgcn_mfma_f32_16x16x32_bf16(al[i], bh[j], acc[i][j], 0, 0, 0);
      }
    __syncthreads();                      // reads done before next stage
  }
}

__global__ __launch_bounds__(NTHR, 1) void kmeans_fused(
    const float* __restrict__ x, const int* __restrict__ init_idx,
    ull_t* __restrict__ cpkv, float* __restrict__ cn2v, int* __restrict__ ids,
    float* __restrict__ psum, float* __restrict__ pcnt,
    float* __restrict__ outp, unsigned* __restrict__ flags,
    unsigned* __restrict__ grep, float* __restrict__ out) {
  __shared__ s8v xhR[4096];               // 64 KB resident swizzled XH image
  __shared__ s8v xlR[4096];               // 64 KB resident swizzled XL image
  __shared__ StU u;
  __shared__ float cns[NK];
  __shared__ float redd[NK * 4];
  __shared__ int   redk[NK * 4];
  __shared__ float gmaxs[NK];
  __shared__ float labvs[NK];
  __shared__ int   labis[NK];
  __shared__ int   cntB[NK];
  __shared__ ushort_t hsm[DIM], lsm[DIM];
  __shared__ float cntsh;

  const int b = blockIdx.x;
  const int t = threadIdx.x;
  const int lane = t & 63;
  const int w  = t >> 6;
  const int wr = w >> 2, wc = w & 3;
  const int g  = lane >> 4, lr = lane & 15;
  const int pbase = b * 128;
  unsigned gen = 1;

  // ---------------- prep: own 128-pt tile -> resident hi/lo LDS image ----------------
  for (int i = 0; i < 4; ++i) {
    int G = i * NTHR + t;                 // granule [0,4096): row = pt, c = 8-dim granule
    int row = G >> 5, c = G & 31;
    const float4* src = (const float4*)(x + ((size_t)pbase + row) * DIM + c * 8);
    float4 fa = src[0], fb = src[1];
    float vv[8] = {fa.x, fa.y, fa.z, fa.w, fb.x, fb.y, fb.z, fb.w};
    s8v vh, vl;
#pragma unroll
    for (int j = 0; j < 8; ++j) {
      unsigned short hh = f2bf(vv[j]);
      vh[j] = (short)hh;
      vl[j] = (short)f2bf(vv[j] - bf2f(hh));
    }
    int pos = c ^ (row & 7);
    *(s8v*)((char*)xhR + row * 512 + pos * 16) = vh;
    *(s8v*)((char*)xlR + row * 512 + pos * 16) = vl;
  }

  // ---------------- init: c0 = x[init_idx] -> packed image v0 + cn2 v0 ----------------
  if (b < NK) {
    float eff = 0.f;
    if (t < DIM) {
      float v = x[init_idx[b] * DIM + t];
      unsigned short hh = f2bf(v);
      unsigned short ll = f2bf(v - bf2f(hh));
      hsm[t] = hh; lsm[t] = ll;
      eff = bf2f(hh) + bf2f(ll);
    }
    __syncthreads();
    u.c.redcn[t] = (t < DIM) ? eff * eff : 0.f;
    if (t < NK) {
      ull_t wv = (ull_t)hsm[2 * t] | ((ull_t)lsm[2 * t] << 16)
               | ((ull_t)hsm[2 * t + 1] << 32) | ((ull_t)lsm[2 * t + 1] << 48);
      cstore64(&cpkv[(size_t)b * 128 + t], wv);
    }
    __syncthreads();
    for (int s = 512; s > 0; s >>= 1) { if (t < s) u.c.redcn[t] += u.c.redcn[t + s]; __syncthreads(); }
    if (t == 0) { cstore(&cn2v[b * 2], u.c.redcn[0]); cstore(&cn2v[b * 2 + 1], 0.f); }
  }
  gbar(flags, grep, gen); ++gen;
  // one-time L2/L1 invalidate: clears any harness-poison (0xAA) lines cached
  // for ws addresses. After this, freshness comes from versioned addresses
  // (within launch) and determinism (across graph replays).
  if (t == 0) __threadfence();
  __syncthreads();

  // ---------------- main loop: A -> B -> C ----------------
  for (int it = 0; it < NITER; ++it) {
    const ull_t*  cpkR = cpkv + (size_t)it * (NK * 128);
    const float*  cn2R = cn2v + (size_t)it * (NK * 2);
    ull_t* cpkW = cpkv + (size_t)(it + 1) * (NK * 128);
    float* cn2W = cn2v + (size_t)(it + 1) * (NK * 2);

    // ---- phase A: assign; ids -> LLC ----
    {
      f4v acc[2][2];
      gemm_core(xhR, xlR, u, cns, t, cpkR, cn2R, acc);
#pragma unroll
      for (int i = 0; i < 2; ++i) {
#pragma unroll
        for (int r = 0; r < 4; ++r) {
          int prow = wr * 32 + i * 16 + g * 4 + r;
          float bd = 1e30f; int bk = 0;
#pragma unroll
          for (int j = 0; j < 2; ++j) {
            int col = wc * 32 + j * 16 + lr;
            float s = cns[col] - 2.f * acc[i][j][r];
            if (s < bd || (s == bd && col < bk)) { bd = s; bk = col; }
          }
#pragma unroll
          for (int msk = 1; msk < 16; msk <<= 1) {
            float od = __shfl_xor(bd, msk, 64);
            int   ok = __shfl_xor(bk, msk, 64);
            if (od < bd || (od == bd && ok < bk)) { bd = od; bk = ok; }
          }
          if (lr == 0) { redd[prow * 4 + wc] = bd; redk[prow * 4 + wc] = bk; }
        }
      }
      __syncthreads();
      if (t < NK) {
        float bd = redd[t * 4]; int bk = redk[t * 4];
#pragma unroll
        for (int q = 1; q < 4; ++q) {
          float dq = redd[t * 4 + q]; int kq = redk[t * 4 + q];
          if (dq < bd || (dq == bd && kq < bk)) { bd = dq; bk = kq; }
        }
        cstorei(&ids[pbase + t], bk);
      }
    }
    gbar(flags, grep, gen); ++gen;

    // ---- phase B: D-split segment-sum (32 pgroups x 8 dgroups), L2-resident x ----
    {
      const int pg = b & 31, dg = b >> 5;
      for (int i = t; i < NK * PAD; i += NTHR) u.b.accB[i] = 0.f;
      if (t < NK) cntB[t] = 0;
      u.b.idsl16[t] = (ushort_t)cloadi(&ids[pg * 1024 + t]);
      __syncthreads();
      const int id = u.b.idsl16[t];
      if (dg == 0) atomicAdd(&cntB[id], 1);
      // NORMAL loads of immutable x: fixed 128KB slice per block -> L2-resident
      const float4* xr = (const float4*)(x + ((size_t)pg * 1024 + t) * DIM + dg * 32);
      float4 v0 = xr[0], v1 = xr[1], v2 = xr[2], v3 = xr[3];
      float4 v4 = xr[4], v5 = xr[5], v6 = xr[6], v7 = xr[7];
      float* ab = &u.b.accB[id * PAD];
      atomicAdd(ab + 0,  v0.x); atomicAdd(ab + 1,  v0.y); atomicAdd(ab + 2,  v0.z); atomicAdd(ab + 3,  v0.w);
      atomicAdd(ab + 4,  v1.x); atomicAdd(ab + 5,  v1.y); atomicAdd(ab + 6,  v1.z); atomicAdd(ab + 7,  v1.w);
      atomicAdd(ab + 8,  v2.x); atomicAdd(ab + 9,  v2.y); atomicAdd(ab + 10, v2.z); atomicAdd(ab + 11, v2.w);
      atomicAdd(ab + 12, v3.x); atomicAdd(ab + 13, v3.y); atomicAdd(ab + 14, v3.z); atomicAdd(ab + 15, v3.w);
      atomicAdd(ab + 16, v4.x); atomicAdd(ab + 17, v4.y); atomicAdd(ab + 18, v4.z); atomicAdd(ab + 19, v4.w);
      atomicAdd(ab + 20, v5.x); atomicAdd(ab + 21, v5.y); atomicAdd(ab + 22, v5.z); atomicAdd(ab + 23, v5.w);
      atomicAdd(ab + 24, v6.x); atomicAdd(ab + 25, v6.y); atomicAdd(ab + 26, v6.z); atomicAdd(ab + 27, v6.w);
      atomicAdd(ab + 28, v7.x); atomicAdd(ab + 29, v7.y); atomicAdd(ab + 30, v7.z); atomicAdd(ab + 31, v7.w);
      __syncthreads();
#pragma unroll
      for (int s2 = 0; s2 < 4; ++s2) {
        int idx = s2 * NTHR + t;          // [0,4096)
        int k2 = idx >> 5, dl = idx & 31;
        cstore(&psum[(((size_t)dg * NK + k2) * 32 + pg) * 32 + dl], u.b.accB[k2 * PAD + dl]);
      }
      if (dg == 0 && t < NK)
        cstore(&pcnt[(size_t)pg * NK + t], (float)cntB[t]);
    }
    gbar(flags, grep, gen); ++gen;

    // ---- phase C: 256 blocks = 128 clusters x 2 D-halves -> version it+1 ----
    {
      const int k = b >> 1, hh2 = b & 1;
      const int dwh = t & 127, pch = t >> 7;   // dim-in-half [0,128), pgroup chunk [0,8)
      const int dgc = hh2 * 4 + (dwh >> 5), dlc = dwh & 31;
      float s = 0.f;
#pragma unroll
      for (int p2 = pch * 4; p2 < pch * 4 + 4; ++p2)
        s += cload(&psum[(((size_t)dgc * NK + k) * 32 + p2) * 32 + dlc]);
      u.c.red4[pch * 128 + dwh] = s;
      float cv = (t < 32) ? cload(&pcnt[(size_t)t * NK + k]) : 0.f;
      if (t < 64) {
#pragma unroll
        for (int m = 1; m < 32; m <<= 1) cv += __shfl_xor(cv, m, 64);
      }
      if (t == 0) cntsh = cv;
      __syncthreads();
      float eff = 0.f;
      if (t < 128) {
        float ssum = 0.f;
#pragma unroll
        for (int ww = 0; ww < 8; ++ww) ssum += u.c.red4[ww * 128 + t];
        float mean = ssum / cntsh;        // NaN if empty, as ref
        unsigned short hh = f2bf(mean);
        unsigned short ll = f2bf(mean - bf2f(hh));
        hsm[t] = hh; lsm[t] = ll;
        eff = bf2f(hh) + bf2f(ll);
      }
      __syncthreads();                    // red4 reads + hsm/lsm writes done
      u.c.redcn[t] = (t < 128) ? eff * eff : 0.f;
      if (t < 64) {
        ull_t wv = (ull_t)hsm[2 * t] | ((ull_t)lsm[2 * t] << 16)
                 | ((ull_t)hsm[2 * t + 1] << 32) | ((ull_t)lsm[2 * t + 1] << 48);
        cstore64(&cpkW[(size_t)k * 128 + hh2 * 64 + t], wv);
      }
      __syncthreads();
      for (int st = 512; st > 0; st >>= 1) { if (t < st) u.c.redcn[t] += u.c.redcn[t + st]; __syncthreads(); }
      if (t == 0) cstore(&cn2W[k * 2 + hh2], u.c.redcn[0]);
    }
    gbar(flags, grep, gen); ++gen;
  }

  // ---------------- final: loss (log-softmax + CE), deterministic reduce ----------------
  {
    f4v acc[2][2];
    gemm_core(xhR, xlR, u, cns, t,
              cpkv + (size_t)NITER * (NK * 128), cn2v + (size_t)NITER * (NK * 2), acc);
#pragma unroll
    for (int i = 0; i < 2; ++i) {
#pragma unroll
      for (int r = 0; r < 4; ++r) {
        int prow = wr * 32 + i * 16 + g * 4 + r;
        float m = -1e30f;
#pragma unroll
        for (int j = 0; j < 2; ++j) m = fmaxf(m, acc[i][j][r]);
#pragma unroll
        for (int msk = 1; msk < 16; msk <<= 1) m = fmaxf(m, __shfl_xor(m, msk, 64));
        if (lr == 0) redd[prow * 4 + wc] = m;
      }
    }
    __syncthreads();
    if (t < NK) {
      float m = redd[t * 4];
#pragma unroll
      for (int q = 1; q < 4; ++q) m = fmaxf(m, redd[t * 4 + q]);
      gmaxs[t] = m;
      labis[t] = cloadi(&ids[pbase + t]);
    }
    __syncthreads();
#pragma unroll
    for (int i = 0; i < 2; ++i) {
#pragma unroll
      for (int r = 0; r < 4; ++r) {
        int prow = wr * 32 + i * 16 + g * 4 + r;
        float m = gmaxs[prow];
        int lab = labis[prow];
        float s = 0.f;
#pragma unroll
        for (int j = 0; j < 2; ++j) {
          int col = wc * 32 + j * 16 + lr;
          float v = acc[i][j][r];
          s += expf(v - m);
          if (col == lab) labvs[prow] = v;
        }
#pragma unroll
        for (int msk = 1; msk < 16; msk <<= 1) s += __shfl_xor(s, msk, 64);
        if (lr == 0) redd[prow * 4 + wc] = s;
      }
    }
    __syncthreads();
    if (t < NK) {
      float se = redd[t * 4] + redd[t * 4 + 1] + redd[t * 4 + 2] + redd[t * 4 + 3];
      float lse = gmaxs[t] + logf(se);
      gmaxs[t] = lse - labvs[t];
    }
    __syncthreads();
    if (t == 0) {
      float tot = 0.f;
      for (int q = 0; q < NK; ++q) tot += gmaxs[q];
      cstore(&outp[b], tot);
    }
  }
  gbar(flags, grep, gen); ++gen;
  if (b == 0) {
    u.c.redcn[t] = (t < NBLK) ? cload(&outp[t]) : 0.f;
    __syncthreads();
    for (int s = 512; s > 0; s >>= 1) { if (t < s) u.c.redcn[t] += u.c.redcn[t + s]; __syncthreads(); }
    if (t == 0) out[0] = u.c.redcn[0] * (1.0f / (float)NPTS);
  }
}

extern "C" void kernel_launch(void* const* d_in, const int* in_sizes, int n_in,
                              void* d_out, int out_size, void* d_ws, size_t ws_size,
                              hipStream_t stream) {
  const float* x        = (const float*)d_in[0];
  const int*   init_idx = (const int*)d_in[1];
  float* out = (float*)d_out;
  char* ws = (char*)d_ws;

  // ws layout (bytes):
  ull_t* cpkv = (ull_t*)(ws);                         // 101 * 131072 = 13238272
  float* cn2v = (float*)(ws + 13238272);              // 101 * 1024 = 103424
  int*   ids  = (int*)(ws + 13341696);                // 131072
  float* psum = (float*)(ws + 13472768);              // 8*128*32*32*4 = 4194304
  float* pcnt = (float*)(ws + 17667072);              // 32*128*4 = 16384
  float* outp = (float*)(ws + 17683456);              // 1024
  unsigned* flags = (unsigned*)(ws + 17684480);       // 256*64B = 16384
  unsigned* grep  = (unsigned*)(ws + 17700864);       // 64*64B = 4096

  // reset barrier state every launch (graph replays include this node)
  hipMemsetAsync(flags, 0, 20480, stream);
  kmeans_fused<<<dim3(NBLK), dim3(NTHR), 0, stream>>>(
      x, init_idx, cpkv, cn2v, ids, psum, pcnt, outp, flags, grep, out);
}